// Round 13
// baseline (2167.944 us; speedup 1.0000x reference)
//
#include <hip/hip_runtime.h>
#include <cstdint>
#include <cstddef>

#define BB 32
#define NN 256
#define PP 3072
#define NG 192   // pixel groups of 16
#define RING 16

typedef unsigned short u16;

// ---- init: gamma0 partials (192 blocks) + state zeroing (32 blocks) ----
__global__ __launch_bounds__(512) void k_init(
    const float* __restrict__ x, const float* __restrict__ W_init,
    double* __restrict__ gpartI, double* __restrict__ memD,
    double* __restrict__ a_g, float* __restrict__ rate,
    u16* __restrict__ maskA, u16* __restrict__ maskB) {
  const int blk = blockIdx.x, tid = threadIdx.x;
  if (blk < 192) {
    const int b = blk / 6, sub = blk % 6;
    __shared__ double xl[512];
    xl[tid] = (double)x[(size_t)b * PP + sub * 512 + tid];
    __syncthreads();
    const int osc = tid & 255, kh = tid >> 8;
    const float* wp = W_init + (size_t)(sub * 512 + kh * 256) * NN + osc;
    const double* xp = xl + kh * 256;
    double a0 = 0, a1 = 0, a2 = 0, a3 = 0, a4 = 0, a5 = 0, a6 = 0, a7 = 0;
    for (int r = 0; r < 256; r += 8) {
      a0 += xp[r + 0] * (double)wp[(size_t)(r + 0) * NN];
      a1 += xp[r + 1] * (double)wp[(size_t)(r + 1) * NN];
      a2 += xp[r + 2] * (double)wp[(size_t)(r + 2) * NN];
      a3 += xp[r + 3] * (double)wp[(size_t)(r + 3) * NN];
      a4 += xp[r + 4] * (double)wp[(size_t)(r + 4) * NN];
      a5 += xp[r + 5] * (double)wp[(size_t)(r + 5) * NN];
      a6 += xp[r + 6] * (double)wp[(size_t)(r + 6) * NN];
      a7 += xp[r + 7] * (double)wp[(size_t)(r + 7) * NN];
    }
    double acc = ((a0 + a1) + (a2 + a3)) + ((a4 + a5) + (a6 + a7));
    __syncthreads();
    __shared__ double hl[256];
    if (kh) hl[osc] = acc;
    __syncthreads();
    if (!kh) gpartI[((size_t)b * 6 + sub) * 256 + osc] = acc + hl[osc];
  } else {
    const int b = blk - 192;
    for (int i = tid; i < PP; i += 512) {
      memD[(size_t)b * PP + i] = 0.0;
      rate[(size_t)b * PP + i] = 0.f;
    }
    for (int i = tid; i < NG; i += 512) {
      maskA[b * NG + i] = 0;
      maskB[b * NG + i] = 0;
    }
    for (int i = tid; i < NN; i += 512) a_g[b * NN + i] = 0.0;
  }
}

// ---- rec gather + gate dot: grid (192 cols, 7 z) ----
// z=0/1/2: W_rec gather over row-third z for ALL 32 batches in one block
//          (512 thr = 4 px-quads x 4 entry-parities x 32 batches). Each
//          W_rec row-tile is read ONCE per (col,third) -> half the traffic
//          of the batch-half decomposition. Barrier-free, shfl_xor reduce.
// z=3..6:  gate-dot blocks: zz=z-3, bh=zz&1, K-half zh=zz>>1 (proven branch).
__global__ __launch_bounds__(512, 6) void k_rec(
    const float* __restrict__ W_rec, const u16* __restrict__ listG,
    const int* __restrict__ cntG, const int* __restrict__ cntB,
    double* __restrict__ recPart, const double* __restrict__ gateG,
    const float* __restrict__ W_gate, double* __restrict__ gatePart) {
  __shared__ double gd[16 * 130];  // 16.6 KB: gate [bl][k] for one K-half
  __shared__ float wt[128 * 16];   // 8 KB: W_gate half-tile [k][pi]
  __shared__ double red[256];
  const int g = blockIdx.x, z = blockIdx.y, j0 = g * 16;
  const int tid = threadIdx.x;

  if (z < 3) {
    // ---- gather: row-third z, all 32 batches, barrier-free ----
    const int qd = tid & 3;        // float4 quad (px 4*qd..4*qd+3)
    const int pr = (tid >> 2) & 3; // entry parity (lane bits 2..3)
    const int b = tid >> 4;        // batch 0..31
    const int beg = (z == 0) ? 0 : cntB[b * 2 + (z - 1)];
    const int end = (z == 2) ? cntG[b] : cntB[b * 2 + z];
    const u16* lst = listG + (size_t)b * PP;
    const float* wp = W_rec + j0 + 4 * qd;

    double a0 = 0, a1 = 0, a2 = 0, a3 = 0;
    int i = beg + pr;
    for (; i + 32 <= end; i += 32) {
      const int r0 = lst[i], r1 = lst[i + 4], r2 = lst[i + 8],
                r3 = lst[i + 12], r4 = lst[i + 16], r5 = lst[i + 20],
                r6 = lst[i + 24], r7 = lst[i + 28];
      const float4 f0 = *(const float4*)(wp + (size_t)r0 * PP);
      const float4 f1 = *(const float4*)(wp + (size_t)r1 * PP);
      const float4 f2 = *(const float4*)(wp + (size_t)r2 * PP);
      const float4 f3 = *(const float4*)(wp + (size_t)r3 * PP);
      const float4 f4 = *(const float4*)(wp + (size_t)r4 * PP);
      const float4 f5 = *(const float4*)(wp + (size_t)r5 * PP);
      const float4 f6 = *(const float4*)(wp + (size_t)r6 * PP);
      const float4 f7 = *(const float4*)(wp + (size_t)r7 * PP);
      a0 += (double)f0.x; a1 += (double)f0.y; a2 += (double)f0.z; a3 += (double)f0.w;
      a0 += (double)f1.x; a1 += (double)f1.y; a2 += (double)f1.z; a3 += (double)f1.w;
      a0 += (double)f2.x; a1 += (double)f2.y; a2 += (double)f2.z; a3 += (double)f2.w;
      a0 += (double)f3.x; a1 += (double)f3.y; a2 += (double)f3.z; a3 += (double)f3.w;
      a0 += (double)f4.x; a1 += (double)f4.y; a2 += (double)f4.z; a3 += (double)f4.w;
      a0 += (double)f5.x; a1 += (double)f5.y; a2 += (double)f5.z; a3 += (double)f5.w;
      a0 += (double)f6.x; a1 += (double)f6.y; a2 += (double)f6.z; a3 += (double)f6.w;
      a0 += (double)f7.x; a1 += (double)f7.y; a2 += (double)f7.z; a3 += (double)f7.w;
    }
    for (; i < end; i += 4) {
      const float4 f = *(const float4*)(wp + (size_t)lst[i] * PP);
      a0 += (double)f.x; a1 += (double)f.y; a2 += (double)f.z; a3 += (double)f.w;
    }
    // reduce over the 4 parities (lane bits 2..3): offsets 4, 8
    a0 += __shfl_xor(a0, 4); a0 += __shfl_xor(a0, 8);
    a1 += __shfl_xor(a1, 4); a1 += __shfl_xor(a1, 8);
    a2 += __shfl_xor(a2, 4); a2 += __shfl_xor(a2, 8);
    a3 += __shfl_xor(a3, 4); a3 += __shfl_xor(a3, 8);
    if (pr == 0) {
      double* dst = recPart + ((size_t)z * BB + b) * PP + j0 + 4 * qd;
      dst[0] = a0; dst[1] = a1; dst[2] = a2; dst[3] = a3;
    }
  } else {
    // ---- gate dot: batch-half bh, K-half zh ----
    const int zz = z - 3, bh = zz & 1, zh = zz >> 1;
    for (int i = tid; i < 2048; i += 512) {
      gd[(i >> 7) * 130 + (i & 127)] =
          gateG[(size_t)(bh * 16 + (i >> 7)) * 256 + zh * 128 + (i & 127)];
      wt[i] = W_gate[(size_t)(zh * 128 + (i >> 4)) * PP + j0 + (i & 15)];
    }
    __syncthreads();
    const int pi = tid & 15, bl = (tid >> 4) & 15, hq = tid >> 8;
    const int b = bh * 16 + bl, p = j0 + pi, pid = tid & 255;
    double s0 = 0, s1 = 0, s2 = 0, s3 = 0, s4 = 0, s5 = 0, s6 = 0, s7 = 0;
    const double* gq = gd + bl * 130 + hq * 64;
    const float* wq = wt + hq * 64 * 16 + pi;
    for (int k = 0; k < 64; k += 8) {
      s0 += gq[k + 0] * (double)wq[(k + 0) * 16];
      s1 += gq[k + 1] * (double)wq[(k + 1) * 16];
      s2 += gq[k + 2] * (double)wq[(k + 2) * 16];
      s3 += gq[k + 3] * (double)wq[(k + 3) * 16];
      s4 += gq[k + 4] * (double)wq[(k + 4) * 16];
      s5 += gq[k + 5] * (double)wq[(k + 5) * 16];
      s6 += gq[k + 6] * (double)wq[(k + 6) * 16];
      s7 += gq[k + 7] * (double)wq[(k + 7) * 16];
    }
    double vg = ((s0 + s1) + (s2 + s3)) + ((s4 + s5) + (s6 + s7));
    if (hq) red[pid] = vg;
    __syncthreads();
    if (!hq) gatePart[((size_t)zh * BB + b) * PP + p] = vg + red[pid];
  }
}

// ---- finalize: pointwise membrane/spike/mask. grid 192, 512 thr ----
__global__ __launch_bounds__(512) void k_fin(
    const u16* __restrict__ mask_rd, u16* __restrict__ mask_wr,
    double* __restrict__ memD, const double* __restrict__ gatePart,
    const double* __restrict__ recPart, float* __restrict__ rate, int accum) {
  const int g = blockIdx.x, tid = threadIdx.x;
  const int pi = tid & 15, b = tid >> 4;
  const int p = g * 16 + pi;
  const size_t idx = (size_t)b * PP + p;
  const double vgs = gatePart[idx] + gatePart[(size_t)BB * PP + idx];
  const double vrs = (recPart[idx] + recPart[(size_t)BB * PP + idx]) +
                     recPart[(size_t)2 * BB * PP + idx];
  const double cur = vgs + 0.1 * vrs;
  const double so = (double)((mask_rd[b * NG + g] >> pi) & 1);
  const double mv = 0.9 * memD[idx] * (1.0 - so) + cur;
  const double sv = (mv - 1.0 > 0.0) ? 1.0 : 0.0;
  memD[idx] = mv;
  if (accum) rate[idx] += (float)sv;
  unsigned long long bal = __ballot(sv > 0.5);
  const int lane = tid & 63;
  if ((lane & 15) == 0)
    mask_wr[b * NG + g] = (u16)((bal >> (16 * (lane >> 4))) & 0xFFFFull);
}

// ---- feedback: mask compaction + partials of a = spk @ W_fb ----
// grid (32 batches, 16 row-splits), 256 thr (one per oscillator column).
__global__ __launch_bounds__(256) void k_fb(
    const u16* __restrict__ spk_mask, u16* __restrict__ listG,
    int* __restrict__ cntG, int* __restrict__ cntB,
    const float* __restrict__ W_fb, double* __restrict__ a_part) {
  const int b = blockIdx.x, y = blockIdx.y, tid = threadIdx.x;
  __shared__ int pc[NG], sc[NG];
  __shared__ u16 m_l[NG];
  __shared__ u16 list_l[PP];
  if (tid < NG) {
    m_l[tid] = spk_mask[b * NG + tid];
    pc[tid] = __popc((unsigned int)m_l[tid]);
    sc[tid] = pc[tid];
  }
  __syncthreads();
  for (int d = 1; d < NG; d <<= 1) {
    int v = 0;
    if (tid < NG) v = sc[tid] + ((tid >= d) ? sc[tid - d] : 0);
    __syncthreads();
    if (tid < NG) sc[tid] = v;
    __syncthreads();
  }
  const int total = sc[NG - 1];
  if (tid < NG) {
    int off = sc[tid] - pc[tid];
    unsigned int m = m_l[tid];
    while (m) {
      int bit = __builtin_ctz(m);
      m &= m - 1;
      list_l[off++] = (u16)(tid * 16 + bit);
    }
  }
  __syncthreads();
  if (y == 0) {
    for (int i = tid; i < total; i += 256) listG[(size_t)b * PP + i] = list_l[i];
    if (tid == 0) {
      cntG[b] = total;
      cntB[b * 2 + 0] = sc[63];   // first list index with row >= 1024
      cntB[b * 2 + 1] = sc[127];  // first list index with row >= 2048
    }
  }
  // partial a: rows i = y (mod 16), 8 streams
  const int j = tid;
  double c0 = 0, c1 = 0, c2 = 0, c3 = 0, c4 = 0, c5 = 0, c6 = 0, c7 = 0;
  int i = y;
  for (; i + 128 <= total; i += 128) {
    c0 += (double)W_fb[(size_t)list_l[i + 0] * NN + j];
    c1 += (double)W_fb[(size_t)list_l[i + 16] * NN + j];
    c2 += (double)W_fb[(size_t)list_l[i + 32] * NN + j];
    c3 += (double)W_fb[(size_t)list_l[i + 48] * NN + j];
    c4 += (double)W_fb[(size_t)list_l[i + 64] * NN + j];
    c5 += (double)W_fb[(size_t)list_l[i + 80] * NN + j];
    c6 += (double)W_fb[(size_t)list_l[i + 96] * NN + j];
    c7 += (double)W_fb[(size_t)list_l[i + 112] * NN + j];
  }
  double acc = ((c0 + c1) + (c2 + c3)) + ((c4 + c5) + (c6 + c7));
  for (; i < total; i += 16) acc += (double)W_fb[(size_t)list_l[i] * NN + j];
  a_part[((size_t)b * 16 + y) * NN + j] = acc;
}

// ---- theta: 5 steps + a finalize + gamma/gate ----
// one block per batch, 512 threads (2-way K-split on W_ro, 8-wave barriers).
__global__ __launch_bounds__(512) void k_theta(
    double* __restrict__ ring, double* __restrict__ gamma_g,
    double* __restrict__ a_g, double* __restrict__ gateG,
    const double* __restrict__ a_part, const float* __restrict__ theta0,
    const float* __restrict__ omega, const float* __restrict__ W_ro,
    const double* __restrict__ gpartI, int* __restrict__ cntG,
    int* __restrict__ cntB, int k2) {
  const int b = blockIdx.x, tid = threadIdx.x;
  const int j = tid & 255, q = tid >> 8;  // q in {0,1}
  const int lane = tid & 63, wid = tid >> 6;
  __shared__ double th[256];
  __shared__ double red[16];
  __shared__ double qpart[256];

  const int s0 = 5 * k2 + 1, s1 = 5 * k2 + 5;
  double new_a = 0.0;
  if (k2 > 0) {
    double s = 0.0;
#pragma unroll
    for (int u = 0; u < 8; ++u)
      s += a_part[((size_t)b * 16 + q * 8 + u) * NN + j];
    if (q) qpart[j] = s;
    __syncthreads();
    if (!q) new_a = tanh(s + qpart[j]);
    __syncthreads();
  }

  double t = 0.0, aj = 0.0, gm = 0.0, om = 0.0;
  if (!q) {
    om = (double)omega[j];
    if (k2 == 0) {
      double s = 0.0;
      for (int c6 = 0; c6 < 6; ++c6) s += gpartI[((size_t)b * 6 + c6) * 256 + j];
      gm = tanh(s);
      t = (double)theta0[b * NN + j];
      ring[0 * BB * NN + b * NN + j] = t;
      if (tid == 0) {
        cntG[b] = 0;
        cntB[b * 2 + 0] = 0;
        cntB[b * 2 + 1] = 0;
      }
    } else {
      t = ring[((s0 - 1) & (RING - 1)) * BB * NN + b * NN + j];
      aj = a_g[b * NN + j];
      gm = gamma_g[b * NN + j];
    }
  }

  for (int s = s0; s <= s1; ++s) {
    if (!q && k2 > 0 && s == s0 + 1) {
      aj = new_a;  // step s0 uses the OLD a
      a_g[b * NN + j] = aj;
    }
    double sn = 0.0, cs = 0.0;
    if (!q) sincos(t, &sn, &cs);
    double r0 = sn, r1 = cs, r2 = aj * sn, r3 = aj * cs;
#pragma unroll
    for (int o = 32; o; o >>= 1) {
      r0 += __shfl_down(r0, o);
      r1 += __shfl_down(r1, o);
      r2 += __shfl_down(r2, o);
      r3 += __shfl_down(r3, o);
    }
    if (lane == 0 && wid < 4) {
      red[wid * 4 + 0] = r0;
      red[wid * 4 + 1] = r1;
      red[wid * 4 + 2] = r2;
      red[wid * 4 + 3] = r3;
    }
    __syncthreads();
    double S = red[0] + red[4] + red[8] + red[12];
    double C = red[1] + red[5] + red[9] + red[13];
    double AS = red[2] + red[6] + red[10] + red[14];
    double AC = red[3] + red[7] + red[11] + red[15];
    __syncthreads();
    if (!q) {
      double base = cs * S - sn * C;
      double wgt = 0.5 * (cs * aj * AS - sn * aj * AC);
      t = t + 0.1 * (om + (1.0 / 256.0) * (base + wgt) + 0.5 * gm);
      ring[(s & (RING - 1)) * BB * NN + b * NN + j] = t;
    }
  }
  if (!q) th[j] = t;
  __syncthreads();
  // gamma = tanh(theta @ W_ro): 2-way K-split x 8 streams
  {
    double c0 = 0, c1 = 0, c2 = 0, c3 = 0, c4 = 0, c5 = 0, c6 = 0, c7 = 0;
    const float* wp = W_ro + j;
    const int i0 = q * 128;
    for (int i = 0; i < 128; i += 8) {
      c0 += th[i0 + i + 0] * (double)wp[(size_t)(i0 + i + 0) * NN];
      c1 += th[i0 + i + 1] * (double)wp[(size_t)(i0 + i + 1) * NN];
      c2 += th[i0 + i + 2] * (double)wp[(size_t)(i0 + i + 2) * NN];
      c3 += th[i0 + i + 3] * (double)wp[(size_t)(i0 + i + 3) * NN];
      c4 += th[i0 + i + 4] * (double)wp[(size_t)(i0 + i + 4) * NN];
      c5 += th[i0 + i + 5] * (double)wp[(size_t)(i0 + i + 5) * NN];
      c6 += th[i0 + i + 6] * (double)wp[(size_t)(i0 + i + 6) * NN];
      c7 += th[i0 + i + 7] * (double)wp[(size_t)(i0 + i + 7) * NN];
    }
    double acc = ((c0 + c1) + (c2 + c3)) + ((c4 + c5) + (c6 + c7));
    if (q) qpart[j] = acc;
    __syncthreads();
    if (!q) {
      double gnew = tanh(acc + qpart[j]);
      gamma_g[b * NN + j] = gnew;
      int sd = s1 - 11;
      if (sd < 0) sd = 0;
      double dly = ring[(sd & (RING - 1)) * BB * NN + b * NN + j];
      double gt = gnew * 0.5 * (1.0 + cos(t - dly));
      gateG[(size_t)b * 256 + j] = gt;
    }
  }
}

// ---- classifier ----
__global__ __launch_bounds__(256) void k_cls(const float* __restrict__ rate,
                                             const float* __restrict__ Wcls,
                                             const float* __restrict__ bcls,
                                             float* __restrict__ out) {
  const int b = blockIdx.x, t = threadIdx.x;
  double acc[10];
#pragma unroll
  for (int c = 0; c < 10; ++c) acc[c] = 0.0;
  for (int p = t; p < PP; p += 256) {
    double r = (double)rate[(size_t)b * PP + p] / 30.0;
#pragma unroll
    for (int c = 0; c < 10; ++c) acc[c] += r * (double)Wcls[(size_t)p * 10 + c];
  }
  __shared__ double sh[10][256];
#pragma unroll
  for (int c = 0; c < 10; ++c) sh[c][t] = acc[c];
  __syncthreads();
  for (int off = 128; off; off >>= 1) {
    if (t < off)
#pragma unroll
      for (int c = 0; c < 10; ++c) sh[c][t] += sh[c][t + off];
    __syncthreads();
  }
  if (t < 10) out[b * 10 + t] = (float)(sh[t][0] + (double)bcls[t]);
}

extern "C" void kernel_launch(void* const* d_in, const int* in_sizes, int n_in,
                              void* d_out, int out_size, void* d_ws,
                              size_t ws_size, hipStream_t stream) {
  const float* x = (const float*)d_in[0];
  const float* theta0 = (const float*)d_in[1];
  const float* W_init = (const float*)d_in[2];
  const float* omega = (const float*)d_in[3];
  const float* W_ro = (const float*)d_in[4];
  const float* W_gate = (const float*)d_in[5];
  const float* W_rec = (const float*)d_in[6];
  const float* W_fb = (const float*)d_in[7];
  const float* W_cls = (const float*)d_in[8];
  const float* b_cls = (const float*)d_in[9];

  char* w = (char*)d_ws;
  size_t off = 0;
  auto alloc = [&](size_t sz) -> void* {
    void* p = w + off;
    off = (off + sz + 255) & ~(size_t)255;
    return p;
  };
  double* ring = (double*)alloc((size_t)RING * BB * NN * 8);
  double* gamma = (double*)alloc((size_t)BB * NN * 8);
  double* a_g = (double*)alloc((size_t)BB * NN * 8);
  double* gateG = (double*)alloc((size_t)BB * NN * 8);
  double* memD = (double*)alloc((size_t)BB * PP * 8);
  float* rate = (float*)alloc((size_t)BB * PP * 4);
  u16* maskA = (u16*)alloc((size_t)BB * NG * 2);
  u16* maskB = (u16*)alloc((size_t)BB * NG * 2);
  u16* listG = (u16*)alloc((size_t)BB * PP * 2);
  int* cntG = (int*)alloc((size_t)BB * 4);
  int* cntB = (int*)alloc((size_t)BB * 2 * 4);
  double* gpartI = (double*)alloc((size_t)BB * 6 * 256 * 8);
  double* a_part = (double*)alloc((size_t)BB * 16 * NN * 8);
  double* recPart = (double*)alloc((size_t)3 * BB * PP * 8);
  double* gatePart = (double*)alloc((size_t)2 * BB * PP * 8);

  k_init<<<224, 512, 0, stream>>>(x, W_init, gpartI, memD, a_g, rate, maskA,
                                  maskB);
  k_theta<<<32, 512, 0, stream>>>(ring, gamma, a_g, gateG, a_part, theta0,
                                  omega, W_ro, gpartI, cntG, cntB, 0);
  for (int k = 1; k < 40; ++k) {
    const u16* mrd = (k & 1) ? maskA : maskB;  // k=1 reads zeros
    u16* mwr = (k & 1) ? maskB : maskA;
    k_rec<<<dim3(192, 7), 512, 0, stream>>>(W_rec, listG, cntG, cntB, recPart,
                                            gateG, W_gate, gatePart);
    k_fin<<<192, 512, 0, stream>>>(mrd, mwr, memD, gatePart, recPart, rate,
                                   (k >= 10) ? 1 : 0);
    k_fb<<<dim3(32, 16), 256, 0, stream>>>(mwr, listG, cntG, cntB, W_fb,
                                           a_part);
    k_theta<<<32, 512, 0, stream>>>(ring, gamma, a_g, gateG, a_part, theta0,
                                    omega, W_ro, gpartI, cntG, cntB, k);
  }
  k_cls<<<32, 256, 0, stream>>>(rate, W_cls, b_cls, (float*)d_out);
}

// Round 14
// 1973.760 us; speedup vs baseline: 1.0984x; 1.0984x over previous
//
#include <hip/hip_runtime.h>
#include <cstdint>
#include <cstddef>

#define BB 32
#define NN 256
#define PP 3072
#define NG 192   // pixel groups of 16
#define RING 16

typedef unsigned short u16;

// ---- init: gamma0 partials (192 blocks) + state zeroing (32 blocks) ----
__global__ __launch_bounds__(512) void k_init(
    const float* __restrict__ x, const float* __restrict__ W_init,
    double* __restrict__ gpartI, double* __restrict__ memD,
    double* __restrict__ a_g, float* __restrict__ rate,
    u16* __restrict__ maskA, u16* __restrict__ maskB, int* __restrict__ cntG,
    int* __restrict__ cntB) {
  const int blk = blockIdx.x, tid = threadIdx.x;
  if (blk < 192) {
    const int b = blk / 6, sub = blk % 6;
    __shared__ double xl[512];
    xl[tid] = (double)x[(size_t)b * PP + sub * 512 + tid];
    __syncthreads();
    const int osc = tid & 255, kh = tid >> 8;
    const float* wp = W_init + (size_t)(sub * 512 + kh * 256) * NN + osc;
    const double* xp = xl + kh * 256;
    double a0 = 0, a1 = 0, a2 = 0, a3 = 0, a4 = 0, a5 = 0, a6 = 0, a7 = 0;
    for (int r = 0; r < 256; r += 8) {
      a0 += xp[r + 0] * (double)wp[(size_t)(r + 0) * NN];
      a1 += xp[r + 1] * (double)wp[(size_t)(r + 1) * NN];
      a2 += xp[r + 2] * (double)wp[(size_t)(r + 2) * NN];
      a3 += xp[r + 3] * (double)wp[(size_t)(r + 3) * NN];
      a4 += xp[r + 4] * (double)wp[(size_t)(r + 4) * NN];
      a5 += xp[r + 5] * (double)wp[(size_t)(r + 5) * NN];
      a6 += xp[r + 6] * (double)wp[(size_t)(r + 6) * NN];
      a7 += xp[r + 7] * (double)wp[(size_t)(r + 7) * NN];
    }
    double acc = ((a0 + a1) + (a2 + a3)) + ((a4 + a5) + (a6 + a7));
    __syncthreads();
    __shared__ double hl[256];
    if (kh) hl[osc] = acc;
    __syncthreads();
    if (!kh) gpartI[((size_t)b * 6 + sub) * 256 + osc] = acc + hl[osc];
  } else {
    const int b = blk - 192;
    for (int i = tid; i < PP; i += 512) {
      memD[(size_t)b * PP + i] = 0.0;
      rate[(size_t)b * PP + i] = 0.f;
    }
    for (int i = tid; i < NG; i += 512) {
      maskA[b * NG + i] = 0;
      maskB[b * NG + i] = 0;
    }
    for (int i = tid; i < NN; i += 512) a_g[b * NN + i] = 0.0;
    if (tid == 0) {
      cntG[b] = 0;
      cntB[b * 2 + 0] = 0;
      cntB[b * 2 + 1] = 0;
    }
  }
}

// ---- merged theta(k) || rec-gather(k+1), NO internal sync ----
// blk 0..31: theta for batch blk (needs a_part(k), ring, gamma/a state).
// blk 32..1183: gather block (g, bh, z) = round-10 decomposition; reads only
// listG/cntG/cntB written by fb(k); writes recPart for fin(k+1). The two
// groups touch disjoint data -> safe in one launch, gather hides theta.
__global__ __launch_bounds__(512) void k_tg(
    double* __restrict__ ring, double* __restrict__ gamma_g,
    double* __restrict__ a_g, double* __restrict__ gateG,
    const double* __restrict__ a_part, const float* __restrict__ theta0,
    const float* __restrict__ omega, const float* __restrict__ W_ro,
    const double* __restrict__ gpartI, const float* __restrict__ W_rec,
    const u16* __restrict__ listG, const int* __restrict__ cntG,
    const int* __restrict__ cntB, double* __restrict__ recPart, int k2) {
  const int blk = blockIdx.x, tid = threadIdx.x;
  __shared__ double th[256];
  __shared__ double red[16];
  __shared__ double qpart[256];

  if (blk >= 32) {
    // ---- gather for iter k2+1 (skip on last iter) ----
    if (k2 >= 39) return;
    const int w = blk - 32;
    const int g = w % 192, bh = (w / 192) & 1, z = w / 384, j0 = g * 16;
    const int qd = tid & 3;        // float4 quad
    const int h = (tid >> 2) & 7;  // entry parity (lane bits 2..4)
    const int bl = tid >> 5;       // batch 0..15
    const int b = bh * 16 + bl;
    const int beg = (z == 0) ? 0 : cntB[b * 2 + (z - 1)];
    const int end = (z == 2) ? cntG[b] : cntB[b * 2 + z];
    const u16* lst = listG + (size_t)b * PP;
    const float* wp = W_rec + j0 + 4 * qd;

    double a0 = 0, a1 = 0, a2 = 0, a3 = 0;
    int i = beg + h;
    for (; i + 32 <= end; i += 32) {
      const int r0 = lst[i], r1 = lst[i + 8], r2 = lst[i + 16],
                r3 = lst[i + 24];
      const float4 f0 = *(const float4*)(wp + (size_t)r0 * PP);
      const float4 f1 = *(const float4*)(wp + (size_t)r1 * PP);
      const float4 f2 = *(const float4*)(wp + (size_t)r2 * PP);
      const float4 f3 = *(const float4*)(wp + (size_t)r3 * PP);
      a0 += (double)f0.x; a1 += (double)f0.y; a2 += (double)f0.z; a3 += (double)f0.w;
      a0 += (double)f1.x; a1 += (double)f1.y; a2 += (double)f1.z; a3 += (double)f1.w;
      a0 += (double)f2.x; a1 += (double)f2.y; a2 += (double)f2.z; a3 += (double)f2.w;
      a0 += (double)f3.x; a1 += (double)f3.y; a2 += (double)f3.z; a3 += (double)f3.w;
    }
    for (; i < end; i += 8) {
      const float4 f = *(const float4*)(wp + (size_t)lst[i] * PP);
      a0 += (double)f.x; a1 += (double)f.y; a2 += (double)f.z; a3 += (double)f.w;
    }
    a0 += __shfl_xor(a0, 4); a0 += __shfl_xor(a0, 8); a0 += __shfl_xor(a0, 16);
    a1 += __shfl_xor(a1, 4); a1 += __shfl_xor(a1, 8); a1 += __shfl_xor(a1, 16);
    a2 += __shfl_xor(a2, 4); a2 += __shfl_xor(a2, 8); a2 += __shfl_xor(a2, 16);
    a3 += __shfl_xor(a3, 4); a3 += __shfl_xor(a3, 8); a3 += __shfl_xor(a3, 16);
    if (h == 0) {
      double* dst = recPart + ((size_t)z * BB + b) * PP + j0 + 4 * qd;
      dst[0] = a0; dst[1] = a1; dst[2] = a2; dst[3] = a3;
    }
    return;
  }

  // ---- theta: 5 steps + a finalize + gamma/gate (batch = blk) ----
  const int b = blk;
  const int j = tid & 255, q = tid >> 8;  // q in {0,1}
  const int lane = tid & 63, wid = tid >> 6;
  const int s0 = 5 * k2 + 1, s1 = 5 * k2 + 5;
  double new_a = 0.0;
  if (k2 > 0) {
    double s = 0.0;
#pragma unroll
    for (int u = 0; u < 8; ++u)
      s += a_part[((size_t)b * 16 + q * 8 + u) * NN + j];
    if (q) qpart[j] = s;
    __syncthreads();
    if (!q) new_a = tanh(s + qpart[j]);
    __syncthreads();
  }

  double t = 0.0, aj = 0.0, gm = 0.0, om = 0.0;
  if (!q) {
    om = (double)omega[j];
    if (k2 == 0) {
      double s = 0.0;
      for (int c6 = 0; c6 < 6; ++c6) s += gpartI[((size_t)b * 6 + c6) * 256 + j];
      gm = tanh(s);
      t = (double)theta0[b * NN + j];
      ring[0 * BB * NN + b * NN + j] = t;
    } else {
      t = ring[((s0 - 1) & (RING - 1)) * BB * NN + b * NN + j];
      aj = a_g[b * NN + j];
      gm = gamma_g[b * NN + j];
    }
  }

  for (int s = s0; s <= s1; ++s) {
    if (!q && k2 > 0 && s == s0 + 1) {
      aj = new_a;  // step s0 uses the OLD a
      a_g[b * NN + j] = aj;
    }
    double sn = 0.0, cs = 0.0;
    if (!q) sincos(t, &sn, &cs);
    double r0 = sn, r1 = cs, r2 = aj * sn, r3 = aj * cs;
#pragma unroll
    for (int o = 32; o; o >>= 1) {
      r0 += __shfl_down(r0, o);
      r1 += __shfl_down(r1, o);
      r2 += __shfl_down(r2, o);
      r3 += __shfl_down(r3, o);
    }
    if (lane == 0 && wid < 4) {
      red[wid * 4 + 0] = r0;
      red[wid * 4 + 1] = r1;
      red[wid * 4 + 2] = r2;
      red[wid * 4 + 3] = r3;
    }
    __syncthreads();
    double S = red[0] + red[4] + red[8] + red[12];
    double C = red[1] + red[5] + red[9] + red[13];
    double AS = red[2] + red[6] + red[10] + red[14];
    double AC = red[3] + red[7] + red[11] + red[15];
    __syncthreads();
    if (!q) {
      double base = cs * S - sn * C;
      double wgt = 0.5 * (cs * aj * AS - sn * aj * AC);
      t = t + 0.1 * (om + (1.0 / 256.0) * (base + wgt) + 0.5 * gm);
      ring[(s & (RING - 1)) * BB * NN + b * NN + j] = t;
    }
  }
  if (!q) th[j] = t;
  __syncthreads();
  // gamma = tanh(theta @ W_ro): 2-way K-split x 8 streams
  {
    double c0 = 0, c1 = 0, c2 = 0, c3 = 0, c4 = 0, c5 = 0, c6 = 0, c7 = 0;
    const float* wp = W_ro + j;
    const int i0 = q * 128;
    for (int i = 0; i < 128; i += 8) {
      c0 += th[i0 + i + 0] * (double)wp[(size_t)(i0 + i + 0) * NN];
      c1 += th[i0 + i + 1] * (double)wp[(size_t)(i0 + i + 1) * NN];
      c2 += th[i0 + i + 2] * (double)wp[(size_t)(i0 + i + 2) * NN];
      c3 += th[i0 + i + 3] * (double)wp[(size_t)(i0 + i + 3) * NN];
      c4 += th[i0 + i + 4] * (double)wp[(size_t)(i0 + i + 4) * NN];
      c5 += th[i0 + i + 5] * (double)wp[(size_t)(i0 + i + 5) * NN];
      c6 += th[i0 + i + 6] * (double)wp[(size_t)(i0 + i + 6) * NN];
      c7 += th[i0 + i + 7] * (double)wp[(size_t)(i0 + i + 7) * NN];
    }
    double acc = ((c0 + c1) + (c2 + c3)) + ((c4 + c5) + (c6 + c7));
    if (q) qpart[j] = acc;
    __syncthreads();
    if (!q) {
      double gnew = tanh(acc + qpart[j]);
      gamma_g[b * NN + j] = gnew;
      int sd = s1 - 11;
      if (sd < 0) sd = 0;
      double dly = ring[(sd & (RING - 1)) * BB * NN + b * NN + j];
      double gt = gnew * 0.5 * (1.0 + cos(t - dly));
      gateG[(size_t)b * 256 + j] = gt;
    }
  }
}

// ---- finalize: gate-dot (LDS-staged gateG + W_gate tile) + rec-sum +
// membrane/spike/mask. grid 192 blocks x 512 thr = 16 px x 32 batches. ----
__global__ __launch_bounds__(512) void k_fin(
    const u16* __restrict__ mask_rd, u16* __restrict__ mask_wr,
    double* __restrict__ memD, const double* __restrict__ gateG,
    const float* __restrict__ W_gate, const double* __restrict__ recPart,
    float* __restrict__ rate, int accum) {
  __shared__ double gd[32 * 258];  // 66 KB: gate [b][k], stride 258 (pad)
  __shared__ float wt[256 * 16];   // 16 KB: W_gate column tile [k][pi]
  const int g = blockIdx.x, tid = threadIdx.x, j0 = g * 16;
  for (int i = tid; i < 8192; i += 512)
    gd[(i >> 8) * 258 + (i & 255)] = gateG[(size_t)(i >> 8) * 256 + (i & 255)];
  for (int i = tid; i < 4096; i += 512)
    wt[i] = W_gate[(size_t)(i >> 4) * PP + j0 + (i & 15)];
  __syncthreads();

  const int pi = tid & 15, b = tid >> 4;
  const double* gq = gd + b * 258;
  const float* wq = wt + pi;
  // four 64-chunks, 8 streams each; combine (c0+c1)+(c2+c3) — identical
  // association to the prior (quarter,half) decomposition.
  double ch0, ch1, ch2, ch3;
  {
    double c[4];
#pragma unroll
    for (int cq = 0; cq < 4; ++cq) {
      const double* gc = gq + cq * 64;
      const float* wc = wq + cq * 64 * 16;
      double s0 = 0, s1 = 0, s2 = 0, s3 = 0, s4 = 0, s5 = 0, s6 = 0, s7 = 0;
      for (int k = 0; k < 64; k += 8) {
        s0 += gc[k + 0] * (double)wc[(k + 0) * 16];
        s1 += gc[k + 1] * (double)wc[(k + 1) * 16];
        s2 += gc[k + 2] * (double)wc[(k + 2) * 16];
        s3 += gc[k + 3] * (double)wc[(k + 3) * 16];
        s4 += gc[k + 4] * (double)wc[(k + 4) * 16];
        s5 += gc[k + 5] * (double)wc[(k + 5) * 16];
        s6 += gc[k + 6] * (double)wc[(k + 6) * 16];
        s7 += gc[k + 7] * (double)wc[(k + 7) * 16];
      }
      c[cq] = ((s0 + s1) + (s2 + s3)) + ((s4 + s5) + (s6 + s7));
    }
    ch0 = c[0]; ch1 = c[1]; ch2 = c[2]; ch3 = c[3];
  }
  const double vgs = (ch0 + ch1) + (ch2 + ch3);

  const int p = j0 + pi;
  const size_t idx = (size_t)b * PP + p;
  const double vrs = (recPart[idx] + recPart[(size_t)BB * PP + idx]) +
                     recPart[(size_t)2 * BB * PP + idx];
  const double cur = vgs + 0.1 * vrs;
  const double so = (double)((mask_rd[b * NG + g] >> pi) & 1);
  const double mv = 0.9 * memD[idx] * (1.0 - so) + cur;
  const double sv = (mv - 1.0 > 0.0) ? 1.0 : 0.0;
  memD[idx] = mv;
  if (accum) rate[idx] += (float)sv;
  unsigned long long bal = __ballot(sv > 0.5);
  const int lane = tid & 63;
  if ((lane & 15) == 0)
    mask_wr[b * NG + g] = (u16)((bal >> (16 * (lane >> 4))) & 0xFFFFull);
}

// ---- feedback: mask compaction + partials of a = spk @ W_fb ----
// grid (32 batches, 16 row-splits), 256 thr (one per oscillator column).
__global__ __launch_bounds__(256) void k_fb(
    const u16* __restrict__ spk_mask, u16* __restrict__ listG,
    int* __restrict__ cntG, int* __restrict__ cntB,
    const float* __restrict__ W_fb, double* __restrict__ a_part) {
  const int b = blockIdx.x, y = blockIdx.y, tid = threadIdx.x;
  __shared__ int pc[NG], sc[NG];
  __shared__ u16 m_l[NG];
  __shared__ u16 list_l[PP];
  if (tid < NG) {
    m_l[tid] = spk_mask[b * NG + tid];
    pc[tid] = __popc((unsigned int)m_l[tid]);
    sc[tid] = pc[tid];
  }
  __syncthreads();
  for (int d = 1; d < NG; d <<= 1) {
    int v = 0;
    if (tid < NG) v = sc[tid] + ((tid >= d) ? sc[tid - d] : 0);
    __syncthreads();
    if (tid < NG) sc[tid] = v;
    __syncthreads();
  }
  const int total = sc[NG - 1];
  if (tid < NG) {
    int off = sc[tid] - pc[tid];
    unsigned int m = m_l[tid];
    while (m) {
      int bit = __builtin_ctz(m);
      m &= m - 1;
      list_l[off++] = (u16)(tid * 16 + bit);
    }
  }
  __syncthreads();
  if (y == 0) {
    for (int i = tid; i < total; i += 256) listG[(size_t)b * PP + i] = list_l[i];
    if (tid == 0) {
      cntG[b] = total;
      cntB[b * 2 + 0] = sc[63];   // first list index with row >= 1024
      cntB[b * 2 + 1] = sc[127];  // first list index with row >= 2048
    }
  }
  // partial a: rows i = y (mod 16), 8 streams
  const int j = tid;
  double c0 = 0, c1 = 0, c2 = 0, c3 = 0, c4 = 0, c5 = 0, c6 = 0, c7 = 0;
  int i = y;
  for (; i + 128 <= total; i += 128) {
    c0 += (double)W_fb[(size_t)list_l[i + 0] * NN + j];
    c1 += (double)W_fb[(size_t)list_l[i + 16] * NN + j];
    c2 += (double)W_fb[(size_t)list_l[i + 32] * NN + j];
    c3 += (double)W_fb[(size_t)list_l[i + 48] * NN + j];
    c4 += (double)W_fb[(size_t)list_l[i + 64] * NN + j];
    c5 += (double)W_fb[(size_t)list_l[i + 80] * NN + j];
    c6 += (double)W_fb[(size_t)list_l[i + 96] * NN + j];
    c7 += (double)W_fb[(size_t)list_l[i + 112] * NN + j];
  }
  double acc = ((c0 + c1) + (c2 + c3)) + ((c4 + c5) + (c6 + c7));
  for (; i < total; i += 16) acc += (double)W_fb[(size_t)list_l[i] * NN + j];
  a_part[((size_t)b * 16 + y) * NN + j] = acc;
}

// ---- classifier ----
__global__ __launch_bounds__(256) void k_cls(const float* __restrict__ rate,
                                             const float* __restrict__ Wcls,
                                             const float* __restrict__ bcls,
                                             float* __restrict__ out) {
  const int b = blockIdx.x, t = threadIdx.x;
  double acc[10];
#pragma unroll
  for (int c = 0; c < 10; ++c) acc[c] = 0.0;
  for (int p = t; p < PP; p += 256) {
    double r = (double)rate[(size_t)b * PP + p] / 30.0;
#pragma unroll
    for (int c = 0; c < 10; ++c) acc[c] += r * (double)Wcls[(size_t)p * 10 + c];
  }
  __shared__ double sh[10][256];
#pragma unroll
  for (int c = 0; c < 10; ++c) sh[c][t] = acc[c];
  __syncthreads();
  for (int off = 128; off; off >>= 1) {
    if (t < off)
#pragma unroll
      for (int c = 0; c < 10; ++c) sh[c][t] += sh[c][t + off];
    __syncthreads();
  }
  if (t < 10) out[b * 10 + t] = (float)(sh[t][0] + (double)bcls[t]);
}

extern "C" void kernel_launch(void* const* d_in, const int* in_sizes, int n_in,
                              void* d_out, int out_size, void* d_ws,
                              size_t ws_size, hipStream_t stream) {
  const float* x = (const float*)d_in[0];
  const float* theta0 = (const float*)d_in[1];
  const float* W_init = (const float*)d_in[2];
  const float* omega = (const float*)d_in[3];
  const float* W_ro = (const float*)d_in[4];
  const float* W_gate = (const float*)d_in[5];
  const float* W_rec = (const float*)d_in[6];
  const float* W_fb = (const float*)d_in[7];
  const float* W_cls = (const float*)d_in[8];
  const float* b_cls = (const float*)d_in[9];

  char* w = (char*)d_ws;
  size_t off = 0;
  auto alloc = [&](size_t sz) -> void* {
    void* p = w + off;
    off = (off + sz + 255) & ~(size_t)255;
    return p;
  };
  double* ring = (double*)alloc((size_t)RING * BB * NN * 8);
  double* gamma = (double*)alloc((size_t)BB * NN * 8);
  double* a_g = (double*)alloc((size_t)BB * NN * 8);
  double* gateG = (double*)alloc((size_t)BB * NN * 8);
  double* memD = (double*)alloc((size_t)BB * PP * 8);
  float* rate = (float*)alloc((size_t)BB * PP * 4);
  u16* maskA = (u16*)alloc((size_t)BB * NG * 2);
  u16* maskB = (u16*)alloc((size_t)BB * NG * 2);
  u16* listG = (u16*)alloc((size_t)BB * PP * 2);
  int* cntG = (int*)alloc((size_t)BB * 4);
  int* cntB = (int*)alloc((size_t)BB * 2 * 4);
  double* gpartI = (double*)alloc((size_t)BB * 6 * 256 * 8);
  double* a_part = (double*)alloc((size_t)BB * 16 * NN * 8);
  double* recPart = (double*)alloc((size_t)3 * BB * PP * 8);

  k_init<<<224, 512, 0, stream>>>(x, W_init, gpartI, memD, a_g, rate, maskA,
                                  maskB, cntG, cntB);
  // theta(0) || gather(1) (cnt=0 -> recPart zeroed)
  k_tg<<<1184, 512, 0, stream>>>(ring, gamma, a_g, gateG, a_part, theta0,
                                 omega, W_ro, gpartI, W_rec, listG, cntG, cntB,
                                 recPart, 0);
  for (int k = 1; k < 40; ++k) {
    const u16* mrd = (k & 1) ? maskA : maskB;  // k=1 reads zeros
    u16* mwr = (k & 1) ? maskB : maskA;
    k_fin<<<192, 512, 0, stream>>>(mrd, mwr, memD, gateG, W_gate, recPart,
                                   rate, (k >= 10) ? 1 : 0);
    k_fb<<<dim3(32, 16), 256, 0, stream>>>(mwr, listG, cntG, cntB, W_fb,
                                           a_part);
    k_tg<<<1184, 512, 0, stream>>>(ring, gamma, a_g, gateG, a_part, theta0,
                                   omega, W_ro, gpartI, W_rec, listG, cntG,
                                   cntB, recPart, k);
  }
  k_cls<<<32, 256, 0, stream>>>(rate, W_cls, b_cls, (float*)d_out);
}